// Round 12
// baseline (1359.570 us; speedup 1.0000x reference)
//
#include <hip/hip_runtime.h>
#include <math.h>

#define IMGD 224
#define HW 50176      // 224*224
#define NK 100
#define NB 8
#define OUT_PER_B 76800   // 100*16*16*3 = 300*256
#define NCHUNK 131        // OpenBLAS k-blocking of 50176: 129x384, 320, 320

// ratio = 10.0 / sqrt(224*224/100) in f64, rounded to f32 when numpy multiplies
// the f32 arange arrays by the weak python scalar.
static __device__ __forceinline__ float ratio_f32() {
  return (float)(10.0 / sqrt(224.0 * 224.0 / 100.0));
}

// ---------- resize matrix A[16][224], jax linear+antialias semantics ----------
__global__ void build_A_kernel(float* __restrict__ A) {
  __shared__ float red[256];
  int p = blockIdx.x;   // 0..15
  int h = threadIdx.x;  // 0..255
  float tri = 0.0f;
  if (h < IMGD) {
    float center = (p + 0.5f) * 14.0f - 0.5f;       // sample_f
    float xd = fabsf(center - (float)h) / 14.0f;    // / kernel_scale
    tri = fmaxf(0.0f, 1.0f - xd);
  }
  red[h] = tri;
  __syncthreads();
  for (int s = 128; s > 0; s >>= 1) {
    if (h < s) red[h] += red[h + s];
    __syncthreads();
  }
  float Z = red[0];
  if (h < IMGD) A[p * IMGD + h] = tri / Z;
}

// ---------- SLIC: grid-init centers (f32, mirroring numpy) + c2 + counters ----------
__global__ void init_centers_kernel(const float* __restrict__ x,
                                    float* __restrict__ centers,
                                    float* __restrict__ c2g,
                                    int* __restrict__ counters) {
  int b = blockIdx.x, k = threadIdx.x;
  if (k == 0) counters[b] = 0;
  if (k >= NK) return;
  int gy = k / 10, gx = k % 10;
  int cy = (int)((gy + 0.5) * 224.0 / 10.0);  // trunc like .astype(int32)
  int cx = (int)((gx + 0.5) * 224.0 / 10.0);
  int i = cy * IMGD + cx;
  const float ratio = ratio_f32();
  float c0 = x[((size_t)b * 3 + 0) * HW + i];
  float c1 = x[((size_t)b * 3 + 1) * HW + i];
  float c2 = x[((size_t)b * 3 + 2) * HW + i];
  float c3 = __fmul_rn((float)cy, ratio);
  float c4 = __fmul_rn((float)cx, ratio);
  float* c = centers + ((size_t)b * NK + k) * 5;
  c[0] = c0; c[1] = c1; c[2] = c2; c[3] = c3; c[4] = c4;
  // c2 = np.sum(centers*centers, axis=1): rounded products, sequential adds
  float s = __fmul_rn(c0, c0);
  s = __fadd_rn(s, __fmul_rn(c1, c1));
  s = __fadd_rn(s, __fmul_rn(c2, c2));
  s = __fadd_rn(s, __fmul_rn(c3, c3));
  s = __fadd_rn(s, __fmul_rn(c4, c4));
  c2g[(size_t)b * NK + k] = s;
}

// distance op sequence — the single source of truth for bit-exactness:
// dot = fmul(f0,c0); fma(f1,c1); fma(f2,c2); fma(f3,c3); fma(f4,c4)
// d   = fsub(fadd(fsq, c2k), fmul(2, dot))
static __device__ __forceinline__ float dist5s(float f0, float f1, float f2,
                                               float f3, float f4, float fsq,
                                               float c0, float c1, float c2,
                                               float c3, float c4, float q) {
  float dot = __fmul_rn(f0, c0);
  dot = __fmaf_rn(f1, c1, dot);
  dot = __fmaf_rn(f2, c2, dot);
  dot = __fmaf_rn(f3, c3, dot);
  dot = __fmaf_rn(f4, c4, dot);
  return __fsub_rn(__fadd_rn(fsq, q), __fmul_rn(2.0f, dot));
}

// fsq = np.sum(feat*feat): rounded products, sequential adds, no FMA
static __device__ __forceinline__ float fsq5(float f0, float f1, float f2,
                                             float f3, float f4) {
  float s = __fmul_rn(f0, f0);
  s = __fadd_rn(s, __fmul_rn(f1, f1));
  s = __fadd_rn(s, __fmul_rn(f2, f2));
  s = __fadd_rn(s, __fmul_rn(f3, f3));
  s = __fadd_rn(s, __fmul_rn(f4, f4));
  return s;
}

// ---------- fused iteration: assign (in-register) + partial + last-block combine ----------
// 128 threads x 3 px = 384 px = one OpenBLAS chunk. Labels never leave the
// block; per-(k,chunk) add chain is ascending-pixel (t = compaction order);
// the 131st-arriving block per b does the ascending-chunk combine.
__global__ void __launch_bounds__(128, 4) iter_kernel(
    const float* __restrict__ x, float* __restrict__ centers,
    float* __restrict__ c2g, float* __restrict__ partials_t,
    int* __restrict__ counters) {
  __shared__ float4 ckp[150];               // pair-packed centers: 3 float4 / 2 k
  __shared__ unsigned int mask[NK * 12];
  __shared__ unsigned short ppk[NK * 12];
  __shared__ float4 cval4[384];
  __shared__ float  cvalf[384];
  __shared__ int cnt[128];
  __shared__ int offx[128];
  __shared__ int wtot;
  __shared__ int lastFlag;
  __shared__ float sums[600];
  int c = blockIdx.x, b = blockIdx.y;
  int tid = threadIdx.x;
  int start = (c < 129) ? c * 384 : 49536 + (c - 129) * 320;
  int len   = (c < 129) ? 384 : 320;

  const float* cb = centers + (size_t)b * NK * 5;
  const float* c2b = c2g + (size_t)b * NK;
  for (int t = tid; t < 150; t += 128) {
    int p = t / 3, r = t - 3 * p;
    int k0 = 2 * p, k1 = 2 * p + 1;
    float4 v;
    if (r == 0)      v = make_float4(cb[k0*5+0], cb[k0*5+1], cb[k0*5+2], cb[k0*5+3]);
    else if (r == 1) v = make_float4(cb[k0*5+4], c2b[k0],    cb[k1*5+0], cb[k1*5+1]);
    else             v = make_float4(cb[k1*5+2], cb[k1*5+3], cb[k1*5+4], c2b[k1]);
    ckp[t] = v;
  }
  for (int t = tid; t < NK * 12; t += 128) mask[t] = 0u;
  __syncthreads();

  const float* x0 = x + (size_t)b * 3 * HW;
  const float ratio = ratio_f32();

  // 3 px/thread: t = tid, tid+128, tid+256 (ascending within chunk)
  float f0[3], f1[3], f2[3], f3[3], f4[3], fq[3], best[3];
  int bk[3]; bool vld[3];
  for (int r = 0; r < 3; ++r) {
    int t = tid + r * 128;
    vld[r] = (t < len);
    int i = start + (vld[r] ? t : 0);
    int y = i / IMGD, xw = i - y * IMGD;
    f0[r] = x0[i]; f1[r] = x0[HW + i]; f2[r] = x0[2 * HW + i];
    f3[r] = __fmul_rn((float)y, ratio);
    f4[r] = __fmul_rn((float)xw, ratio);
    fq[r] = fsq5(f0[r], f1[r], f2[r], f3[r], f4[r]);
    best[r] = 3.4e38f; bk[r] = 0;
  }
  for (int p = 0; p < 50; ++p) {   // k = 2p, 2p+1 ascending
    float4 v0 = ckp[3 * p], v1 = ckp[3 * p + 1], v2 = ckp[3 * p + 2];
    for (int r = 0; r < 3; ++r) {
      float d0 = dist5s(f0[r], f1[r], f2[r], f3[r], f4[r], fq[r],
                        v0.x, v0.y, v0.z, v0.w, v1.x, v1.y);
      if (d0 < best[r]) { best[r] = d0; bk[r] = 2 * p; }      // first-index wins
      float d1 = dist5s(f0[r], f1[r], f2[r], f3[r], f4[r], fq[r],
                        v1.z, v1.w, v2.x, v2.y, v2.z, v2.w);
      if (d1 < best[r]) { best[r] = d1; bk[r] = 2 * p + 1; }
    }
  }
  for (int r = 0; r < 3; ++r) {
    int t = tid + r * 128;
    if (vld[r]) atomicOr(&mask[bk[r] * 12 + (t >> 5)], 1u << (t & 31));
  }
  __syncthreads();

  // per-k cumulative popcounts
  int myCnt = 0;
  if (tid < NK) {
    int s = 0;
    for (int g = 0; g < 12; ++g) {
      ppk[tid * 12 + g] = (unsigned short)s;
      s += __popc(mask[tid * 12 + g]);
    }
    myCnt = s;
  }
  cnt[tid] = myCnt;
  __syncthreads();

  // inclusive prefix over 128 counts: shfl per wave + cross-wave fixup
  int v = cnt[tid];
  for (int d = 1; d < 64; d <<= 1) {
    int u = __shfl_up(v, d, 64);
    if ((tid & 63) >= d) v += u;
  }
  if (tid == 63) wtot = v;
  __syncthreads();
  if (tid >= 64) v += wtot;
  offx[tid] = v;
  __syncthreads();

  // stable VALUE scatter
  for (int r = 0; r < 3; ++r) {
    int t = tid + r * 128;
    if (vld[r]) {
      int g = t >> 5, j = t & 31;
      int rank = ppk[bk[r] * 12 + g] + __popc(mask[bk[r] * 12 + g] & ((1u << j) - 1u));
      int pos = offx[bk[r]] - cnt[bk[r]] + rank;
      cval4[pos] = make_float4(f0[r], f1[r], f2[r], f3[r]);
      cvalf[pos] = f4[r];
    }
  }
  __syncthreads();

  // scan: thread k walks its consecutive compacted range (ascending t)
  if (tid < NK) {
    int n = cnt[tid];
    int base = offx[tid] - n;
    float s0 = 0.f, s1 = 0.f, s2 = 0.f, s3 = 0.f, s4 = 0.f, s5 = 0.f;
    for (int m = 0; m < n; ++m) {
      float4 vv = cval4[base + m];
      float ww = cvalf[base + m];
      s0 = __fadd_rn(s0, vv.x);
      s1 = __fadd_rn(s1, vv.y);
      s2 = __fadd_rn(s2, vv.z);
      s3 = __fadd_rn(s3, vv.w);
      s4 = __fadd_rn(s4, ww);
      s5 += 1.0f;
    }
    float* pp = partials_t + ((size_t)(b * NK + tid) * 6) * NCHUNK + c;
    pp[0 * NCHUNK] = s0; pp[1 * NCHUNK] = s1; pp[2 * NCHUNK] = s2;
    pp[3 * NCHUNK] = s3; pp[4 * NCHUNK] = s4; pp[5 * NCHUNK] = s5;
    __threadfence();                 // release: make partials visible device-wide
  }
  __syncthreads();
  if (tid == 0) {
    int old = atomicAdd(&counters[b], 1);   // device-scope
    lastFlag = ((old % NCHUNK) == NCHUNK - 1) ? 1 : 0;
  }
  __syncthreads();
  if (!lastFlag) return;
  __threadfence();                   // acquire: see all blocks' partials

  // combine: 600 chains (k,j), ascending chunk order — same as ref blocked sum
  for (int t = tid; t < 600; t += 128) {
    int k = t / 6, j = t - 6 * k;
    const float* basep = partials_t + ((size_t)(b * NK + k) * 6 + j) * NCHUNK;
    float s = basep[0];
    for (int cc = 1; cc < NCHUNK; ++cc) s = __fadd_rn(s, basep[cc]);
    sums[t] = s;
  }
  __syncthreads();
  if (tid < NK) {
    float cntv = sums[tid * 6 + 5];
    float* cc2 = centers + ((size_t)b * NK + tid) * 5;
    float n0, n1, n2, n3, n4;
    if (cntv > 0.0f) {               // where(cnt>0, new, centers)
      float m = fmaxf(cntv, 1.0f);   // np.maximum(cnt,1.0): exact int in f32
      n0 = __fdiv_rn(sums[tid * 6 + 0], m);
      n1 = __fdiv_rn(sums[tid * 6 + 1], m);
      n2 = __fdiv_rn(sums[tid * 6 + 2], m);
      n3 = __fdiv_rn(sums[tid * 6 + 3], m);
      n4 = __fdiv_rn(sums[tid * 6 + 4], m);
      cc2[0] = n0; cc2[1] = n1; cc2[2] = n2; cc2[3] = n3; cc2[4] = n4;
    } else {
      n0 = cc2[0]; n1 = cc2[1]; n2 = cc2[2]; n3 = cc2[3]; n4 = cc2[4];
    }
    // c2 = sum(centers*centers): rounded products, sequential adds
    float t0 = __fmul_rn(n0, n0);
    t0 = __fadd_rn(t0, __fmul_rn(n1, n1));
    t0 = __fadd_rn(t0, __fmul_rn(n2, n2));
    t0 = __fadd_rn(t0, __fmul_rn(n3, n3));
    t0 = __fadd_rn(t0, __fmul_rn(n4, n4));
    c2g[(size_t)b * NK + tid] = t0;
  }
}

// ---------- final full-image assignment: 2 px/thread, k-batched by 4 ----------
__global__ void __launch_bounds__(256) assign_kernel(
    const float* __restrict__ x, const float* __restrict__ centers,
    const float* __restrict__ c2g, int* __restrict__ labels) {
  __shared__ float4 ck4[NK];
  __shared__ float2 ck2[NK];
  int b = blockIdx.y;
  int tid = threadIdx.x;
  int base = blockIdx.x * 512;   // grid.x = 98 -> 98*512 = 50176 exact

  const float* cb = centers + (size_t)b * NK * 5;
  const float* c2b = c2g + (size_t)b * NK;
  for (int k = tid; k < NK; k += 256) {
    ck4[k] = make_float4(cb[k * 5 + 0], cb[k * 5 + 1], cb[k * 5 + 2], cb[k * 5 + 3]);
    ck2[k] = make_float2(cb[k * 5 + 4], c2b[k]);
  }
  __syncthreads();

  const float* x0 = x + (size_t)b * 3 * HW;
  const float ratio = ratio_f32();
  float f0[2], f1[2], f2[2], f3[2], f4[2], fq[2];
  float best[2]; int bk[2];
  for (int r = 0; r < 2; ++r) {
    int i = base + r * 256 + tid;   // coalesced
    int y = i / IMGD, xw = i - y * IMGD;
    f0[r] = x0[i]; f1[r] = x0[HW + i]; f2[r] = x0[2 * HW + i];
    f3[r] = __fmul_rn((float)y, ratio);
    f4[r] = __fmul_rn((float)xw, ratio);
    fq[r] = fsq5(f0[r], f1[r], f2[r], f3[r], f4[r]);
    best[r] = 3.4e38f; bk[r] = 0;
  }
  for (int kb = 0; kb < NK; kb += 4) {
    float4 a4[4]; float2 a2[4];
    for (int kk = 0; kk < 4; ++kk) { a4[kk] = ck4[kb + kk]; a2[kk] = ck2[kb + kk]; }
    for (int kk = 0; kk < 4; ++kk) {
      for (int r = 0; r < 2; ++r) {
        float d = dist5s(f0[r], f1[r], f2[r], f3[r], f4[r], fq[r],
                         a4[kk].x, a4[kk].y, a4[kk].z, a4[kk].w, a2[kk].x, a2[kk].y);
        if (d < best[r]) { best[r] = d; bk[r] = kb + kk; }  // first-index wins
      }
    }
  }
  int* lb = labels + (size_t)b * HW;
  for (int r = 0; r < 2; ++r) lb[base + r * 256 + tid] = bk[r];
}

// ---------- embed: block = (b,p,q); LDS bins per (k,c); direct stores ----------
__global__ void __launch_bounds__(256) embed_kernel(
    const float* __restrict__ x, const int* __restrict__ labels,
    const float* __restrict__ A, float* __restrict__ out) {
  __shared__ float sk[NK * 3];
  int b = blockIdx.y;
  int p = blockIdx.x >> 4;
  int q = blockIdx.x & 15;
  int tid = threadIdx.x;
  for (int t = tid; t < NK * 3; t += 256) sk[t] = 0.0f;
  __syncthreads();

  // A[p,h] support: h in [14p-7, 14p+20] clipped
  int h0 = max(0, 14 * p - 7), h1 = min(IMGD - 1, 14 * p + 20);
  int w0 = max(0, 14 * q - 7), w1 = min(IMGD - 1, 14 * q + 20);
  int hl = h1 - h0 + 1, wl = w1 - w0 + 1;
  int n = hl * wl;

  const float* xb = x + (size_t)b * 3 * HW;
  const int* lb = labels + (size_t)b * HW;
  const float* Ap = A + p * IMGD;
  const float* Aq = A + q * IMGD;

  for (int idx = tid; idx < n; idx += 256) {
    int dh = idx / wl;
    int hh = h0 + dh;
    int ww = w0 + (idx - dh * wl);
    int i = hh * IMGD + ww;
    float wgt = Ap[hh] * Aq[ww];
    int k = lb[i];
    atomicAdd(&sk[k * 3 + 0], wgt * xb[i]);
    atomicAdd(&sk[k * 3 + 1], wgt * xb[HW + i]);
    atomicAdd(&sk[k * 3 + 2], wgt * xb[2 * HW + i]);
  }
  __syncthreads();

  float* outb = out + (size_t)b * OUT_PER_B;
  int base = p * 48 + q * 3;
  for (int t = tid; t < NK * 3; t += 256) {
    int k = t / 3, c = t - 3 * k;
    int f = k * 768 + base + c;           // flat [K,P,P,C] index
    outb[(f & 255) * 300 + (f >> 8)] = sk[t];  // view(B,300,256) + transpose
  }
}

extern "C" void kernel_launch(void* const* d_in, const int* in_sizes, int n_in,
                              void* d_out, int out_size, void* d_ws, size_t ws_size,
                              hipStream_t stream) {
  const float* x = (const float*)d_in[0];
  float* out = (float*)d_out;
  char* ws = (char*)d_ws;
  // ws layout:
  float* A        = (float*)(ws);              // 14336 B
  float* centers  = (float*)(ws + 16384);      // 16000 B
  float* c2g      = (float*)(ws + 49152);      // 3200 B
  int*   labels   = (int*)(ws + 90112);        // 1605632 B
  float* partials = (float*)(ws + 1703936);    // 8*100*6*131*4 = 2515200 B
  int*   counters = (int*)(ws + 4220928);      // 8 ints

  build_A_kernel<<<16, 256, 0, stream>>>(A);
  init_centers_kernel<<<NB, 128, 0, stream>>>(x, centers, c2g, counters);

  dim3 cgrid(NCHUNK, NB);         // 131 x 8
  for (int it = 0; it < 10; ++it) {
    iter_kernel<<<cgrid, 128, 0, stream>>>(x, centers, c2g, partials, counters);
  }
  dim3 agrid(98, NB);             // 98*512 = 50176 exact
  assign_kernel<<<agrid, 256, 0, stream>>>(x, centers, c2g, labels);

  dim3 egrid(256, NB);            // (p*16+q) x b
  embed_kernel<<<egrid, 256, 0, stream>>>(x, labels, A, out);
}

// Round 13
// 367.118 us; speedup vs baseline: 3.7034x; 3.7034x over previous
//
#include <hip/hip_runtime.h>
#include <math.h>

#define IMGD 224
#define HW 50176      // 224*224
#define NK 100
#define NB 8
#define OUT_PER_B 76800   // 100*16*16*3 = 300*256
#define NCHUNK 131        // OpenBLAS k-blocking of 50176: 129x384, 320, 320

// ratio = 10.0 / sqrt(224*224/100) in f64, rounded to f32 when numpy multiplies
// the f32 arange arrays by the weak python scalar.
static __device__ __forceinline__ float ratio_f32() {
  return (float)(10.0 / sqrt(224.0 * 224.0 / 100.0));
}

// ---------- resize matrix A[16][224], jax linear+antialias semantics ----------
__global__ void build_A_kernel(float* __restrict__ A) {
  __shared__ float red[256];
  int p = blockIdx.x;   // 0..15
  int h = threadIdx.x;  // 0..255
  float tri = 0.0f;
  if (h < IMGD) {
    float center = (p + 0.5f) * 14.0f - 0.5f;       // sample_f
    float xd = fabsf(center - (float)h) / 14.0f;    // / kernel_scale
    tri = fmaxf(0.0f, 1.0f - xd);
  }
  red[h] = tri;
  __syncthreads();
  for (int s = 128; s > 0; s >>= 1) {
    if (h < s) red[h] += red[h + s];
    __syncthreads();
  }
  float Z = red[0];
  if (h < IMGD) A[p * IMGD + h] = tri / Z;
}

// ---------- SLIC: grid-init centers (f32, mirroring numpy) + c2 ----------
__global__ void init_centers_kernel(const float* __restrict__ x,
                                    float* __restrict__ centers,
                                    float* __restrict__ c2g) {
  int b = blockIdx.x, k = threadIdx.x;
  if (k >= NK) return;
  int gy = k / 10, gx = k % 10;
  int cy = (int)((gy + 0.5) * 224.0 / 10.0);  // trunc like .astype(int32)
  int cx = (int)((gx + 0.5) * 224.0 / 10.0);
  int i = cy * IMGD + cx;
  const float ratio = ratio_f32();
  float c0 = x[((size_t)b * 3 + 0) * HW + i];
  float c1 = x[((size_t)b * 3 + 1) * HW + i];
  float c2 = x[((size_t)b * 3 + 2) * HW + i];
  float c3 = __fmul_rn((float)cy, ratio);
  float c4 = __fmul_rn((float)cx, ratio);
  float* c = centers + ((size_t)b * NK + k) * 5;
  c[0] = c0; c[1] = c1; c[2] = c2; c[3] = c3; c[4] = c4;
  // c2 = np.sum(centers*centers, axis=1): rounded products, sequential adds
  float s = __fmul_rn(c0, c0);
  s = __fadd_rn(s, __fmul_rn(c1, c1));
  s = __fadd_rn(s, __fmul_rn(c2, c2));
  s = __fadd_rn(s, __fmul_rn(c3, c3));
  s = __fadd_rn(s, __fmul_rn(c4, c4));
  c2g[(size_t)b * NK + k] = s;
}

// distance op sequence — the single source of truth for bit-exactness:
// dot = fmul(f0,c0); fma(f1,c1); fma(f2,c2); fma(f3,c3); fma(f4,c4)
// d   = fsub(fadd(fsq, c2k), fmul(2, dot))
static __device__ __forceinline__ float dist5s(float f0, float f1, float f2,
                                               float f3, float f4, float fsq,
                                               float c0, float c1, float c2,
                                               float c3, float c4, float q) {
  float dot = __fmul_rn(f0, c0);
  dot = __fmaf_rn(f1, c1, dot);
  dot = __fmaf_rn(f2, c2, dot);
  dot = __fmaf_rn(f3, c3, dot);
  dot = __fmaf_rn(f4, c4, dot);
  return __fsub_rn(__fadd_rn(fsq, q), __fmul_rn(2.0f, dot));
}

// fsq = np.sum(feat*feat): rounded products, sequential adds, no FMA
static __device__ __forceinline__ float fsq5(float f0, float f1, float f2,
                                             float f3, float f4) {
  float s = __fmul_rn(f0, f0);
  s = __fadd_rn(s, __fmul_rn(f1, f1));
  s = __fadd_rn(s, __fmul_rn(f2, f2));
  s = __fadd_rn(s, __fmul_rn(f3, f3));
  s = __fadd_rn(s, __fmul_rn(f4, f4));
  return s;
}

// ---------- fused assign+partial: one block = one OpenBLAS chunk ----------
// 128 threads x 3 px = 384 px. Labels never leave the block; per-(k,chunk)
// add chain ascending-pixel via stable counting-sort value compaction.
// NO cross-block combine here: kernel boundary = cheap XCD coherence point
// (R12 showed an in-kernel __threadfence costs an L2 flush: 19.7 MB writes).
__global__ void __launch_bounds__(128, 4) iter_kernel(
    const float* __restrict__ x, const float* __restrict__ centers,
    const float* __restrict__ c2g, float* __restrict__ partials_t) {
  __shared__ float4 ckp[150];               // pair-packed centers: 3 float4 / 2 k
  __shared__ unsigned int mask[NK * 12];
  __shared__ unsigned short ppk[NK * 12];
  __shared__ float4 cval4[384];
  __shared__ float  cvalf[384];
  __shared__ int cnt[128];
  __shared__ int offx[128];
  __shared__ int wtot;
  int c = blockIdx.x, b = blockIdx.y;
  int tid = threadIdx.x;
  int start = (c < 129) ? c * 384 : 49536 + (c - 129) * 320;
  int len   = (c < 129) ? 384 : 320;

  const float* cb = centers + (size_t)b * NK * 5;
  const float* c2b = c2g + (size_t)b * NK;
  for (int t = tid; t < 150; t += 128) {
    int p = t / 3, r = t - 3 * p;
    int k0 = 2 * p, k1 = 2 * p + 1;
    float4 v;
    if (r == 0)      v = make_float4(cb[k0*5+0], cb[k0*5+1], cb[k0*5+2], cb[k0*5+3]);
    else if (r == 1) v = make_float4(cb[k0*5+4], c2b[k0],    cb[k1*5+0], cb[k1*5+1]);
    else             v = make_float4(cb[k1*5+2], cb[k1*5+3], cb[k1*5+4], c2b[k1]);
    ckp[t] = v;
  }
  for (int t = tid; t < NK * 12; t += 128) mask[t] = 0u;
  __syncthreads();

  const float* x0 = x + (size_t)b * 3 * HW;
  const float ratio = ratio_f32();

  // 3 px/thread: t = tid, tid+128, tid+256 (ascending within chunk)
  float f0[3], f1[3], f2[3], f3[3], f4[3], fq[3], best[3];
  int bk[3]; bool vld[3];
  for (int r = 0; r < 3; ++r) {
    int t = tid + r * 128;
    vld[r] = (t < len);
    int i = start + (vld[r] ? t : 0);
    int y = i / IMGD, xw = i - y * IMGD;
    f0[r] = x0[i]; f1[r] = x0[HW + i]; f2[r] = x0[2 * HW + i];
    f3[r] = __fmul_rn((float)y, ratio);
    f4[r] = __fmul_rn((float)xw, ratio);
    fq[r] = fsq5(f0[r], f1[r], f2[r], f3[r], f4[r]);
    best[r] = 3.4e38f; bk[r] = 0;
  }
  for (int p = 0; p < 50; ++p) {   // k = 2p, 2p+1 ascending
    float4 v0 = ckp[3 * p], v1 = ckp[3 * p + 1], v2 = ckp[3 * p + 2];
    for (int r = 0; r < 3; ++r) {
      float d0 = dist5s(f0[r], f1[r], f2[r], f3[r], f4[r], fq[r],
                        v0.x, v0.y, v0.z, v0.w, v1.x, v1.y);
      if (d0 < best[r]) { best[r] = d0; bk[r] = 2 * p; }      // first-index wins
      float d1 = dist5s(f0[r], f1[r], f2[r], f3[r], f4[r], fq[r],
                        v1.z, v1.w, v2.x, v2.y, v2.z, v2.w);
      if (d1 < best[r]) { best[r] = d1; bk[r] = 2 * p + 1; }
    }
  }
  for (int r = 0; r < 3; ++r) {
    int t = tid + r * 128;
    if (vld[r]) atomicOr(&mask[bk[r] * 12 + (t >> 5)], 1u << (t & 31));
  }
  __syncthreads();

  // per-k cumulative popcounts
  int myCnt = 0;
  if (tid < NK) {
    int s = 0;
    for (int g = 0; g < 12; ++g) {
      ppk[tid * 12 + g] = (unsigned short)s;
      s += __popc(mask[tid * 12 + g]);
    }
    myCnt = s;
  }
  cnt[tid] = myCnt;
  __syncthreads();

  // inclusive prefix over 128 counts: shfl per wave + cross-wave fixup
  int v = cnt[tid];
  for (int d = 1; d < 64; d <<= 1) {
    int u = __shfl_up(v, d, 64);
    if ((tid & 63) >= d) v += u;
  }
  if (tid == 63) wtot = v;
  __syncthreads();
  if (tid >= 64) v += wtot;
  offx[tid] = v;
  __syncthreads();

  // stable VALUE scatter
  for (int r = 0; r < 3; ++r) {
    int t = tid + r * 128;
    if (vld[r]) {
      int g = t >> 5, j = t & 31;
      int rank = ppk[bk[r] * 12 + g] + __popc(mask[bk[r] * 12 + g] & ((1u << j) - 1u));
      int pos = offx[bk[r]] - cnt[bk[r]] + rank;
      cval4[pos] = make_float4(f0[r], f1[r], f2[r], f3[r]);
      cvalf[pos] = f4[r];
    }
  }
  __syncthreads();

  // scan: thread k walks its consecutive compacted range (ascending t)
  if (tid < NK) {
    int n = cnt[tid];
    int base = offx[tid] - n;
    float s0 = 0.f, s1 = 0.f, s2 = 0.f, s3 = 0.f, s4 = 0.f, s5 = 0.f;
    for (int m = 0; m < n; ++m) {
      float4 vv = cval4[base + m];
      float ww = cvalf[base + m];
      s0 = __fadd_rn(s0, vv.x);
      s1 = __fadd_rn(s1, vv.y);
      s2 = __fadd_rn(s2, vv.z);
      s3 = __fadd_rn(s3, vv.w);
      s4 = __fadd_rn(s4, ww);
      s5 += 1.0f;
    }
    // transposed layout [b][k][j][c] so combine reads contiguous
    float* pp = partials_t + ((size_t)(b * NK + tid) * 6) * NCHUNK + c;
    pp[0 * NCHUNK] = s0; pp[1 * NCHUNK] = s1; pp[2 * NCHUNK] = s2;
    pp[3 * NCHUNK] = s3; pp[4 * NCHUNK] = s4; pp[5 * NCHUNK] = s5;
  }
}

// ---------- combine: one block per (b,k); LDS-staged 131-chains ----------
// 128 threads stage the 786 contiguous partials (parallel, coalesced); then
// 6 threads run the sequential ascending-chunk chains LDS-fed. Same add
// order as the blocked-sgemm reference.
__global__ void __launch_bounds__(128) combine_update_kernel(
    float* __restrict__ centers, const float* __restrict__ partials_t,
    float* __restrict__ c2g) {
  __shared__ float st[6 * NCHUNK];
  __shared__ float sums[6];
  __shared__ float newc[5];
  int bk = blockIdx.x;                 // b*NK + k
  int tid = threadIdx.x;
  const float* base = partials_t + (size_t)bk * 6 * NCHUNK;
  for (int t = tid; t < 6 * NCHUNK; t += 128) st[t] = base[t];
  __syncthreads();
  if (tid < 6) {
    const float* row = st + tid * NCHUNK;
    float s = row[0];                  // C = 0 + chunk0 (exact)
    for (int c = 1; c < NCHUNK; ++c) s = __fadd_rn(s, row[c]);
    sums[tid] = s;
  }
  __syncthreads();
  float cntv = sums[5];
  float* cc = centers + (size_t)bk * 5;
  if (tid < 5) {
    float v;
    if (cntv > 0.0f) {                 // where(cnt>0, new, centers)
      float m = fmaxf(cntv, 1.0f);     // np.maximum(cnt,1.0): exact int in f32
      v = __fdiv_rn(sums[tid], m);
      cc[tid] = v;
    } else {
      v = cc[tid];                     // unchanged center
    }
    newc[tid] = v;
  }
  __syncthreads();
  if (tid == 0) {
    // c2 = sum(centers*centers): rounded products, sequential adds
    float t0 = __fmul_rn(newc[0], newc[0]);
    t0 = __fadd_rn(t0, __fmul_rn(newc[1], newc[1]));
    t0 = __fadd_rn(t0, __fmul_rn(newc[2], newc[2]));
    t0 = __fadd_rn(t0, __fmul_rn(newc[3], newc[3]));
    t0 = __fadd_rn(t0, __fmul_rn(newc[4], newc[4]));
    c2g[bk] = t0;
  }
}

// ---------- final full-image assignment: 2 px/thread, k-batched by 4 ----------
__global__ void __launch_bounds__(256) assign_kernel(
    const float* __restrict__ x, const float* __restrict__ centers,
    const float* __restrict__ c2g, int* __restrict__ labels) {
  __shared__ float4 ck4[NK];
  __shared__ float2 ck2[NK];
  int b = blockIdx.y;
  int tid = threadIdx.x;
  int base = blockIdx.x * 512;   // grid.x = 98 -> 98*512 = 50176 exact

  const float* cb = centers + (size_t)b * NK * 5;
  const float* c2b = c2g + (size_t)b * NK;
  for (int k = tid; k < NK; k += 256) {
    ck4[k] = make_float4(cb[k * 5 + 0], cb[k * 5 + 1], cb[k * 5 + 2], cb[k * 5 + 3]);
    ck2[k] = make_float2(cb[k * 5 + 4], c2b[k]);
  }
  __syncthreads();

  const float* x0 = x + (size_t)b * 3 * HW;
  const float ratio = ratio_f32();
  float f0[2], f1[2], f2[2], f3[2], f4[2], fq[2];
  float best[2]; int bk[2];
  for (int r = 0; r < 2; ++r) {
    int i = base + r * 256 + tid;   // coalesced
    int y = i / IMGD, xw = i - y * IMGD;
    f0[r] = x0[i]; f1[r] = x0[HW + i]; f2[r] = x0[2 * HW + i];
    f3[r] = __fmul_rn((float)y, ratio);
    f4[r] = __fmul_rn((float)xw, ratio);
    fq[r] = fsq5(f0[r], f1[r], f2[r], f3[r], f4[r]);
    best[r] = 3.4e38f; bk[r] = 0;
  }
  for (int kb = 0; kb < NK; kb += 4) {
    float4 a4[4]; float2 a2[4];
    for (int kk = 0; kk < 4; ++kk) { a4[kk] = ck4[kb + kk]; a2[kk] = ck2[kb + kk]; }
    for (int kk = 0; kk < 4; ++kk) {
      for (int r = 0; r < 2; ++r) {
        float d = dist5s(f0[r], f1[r], f2[r], f3[r], f4[r], fq[r],
                         a4[kk].x, a4[kk].y, a4[kk].z, a4[kk].w, a2[kk].x, a2[kk].y);
        if (d < best[r]) { best[r] = d; bk[r] = kb + kk; }  // first-index wins
      }
    }
  }
  int* lb = labels + (size_t)b * HW;
  for (int r = 0; r < 2; ++r) lb[base + r * 256 + tid] = bk[r];
}

// ---------- embed: block = (b,p,q); LDS bins per (k,c); direct stores ----------
__global__ void __launch_bounds__(256) embed_kernel(
    const float* __restrict__ x, const int* __restrict__ labels,
    const float* __restrict__ A, float* __restrict__ out) {
  __shared__ float sk[NK * 3];
  int b = blockIdx.y;
  int p = blockIdx.x >> 4;
  int q = blockIdx.x & 15;
  int tid = threadIdx.x;
  for (int t = tid; t < NK * 3; t += 256) sk[t] = 0.0f;
  __syncthreads();

  // A[p,h] support: h in [14p-7, 14p+20] clipped
  int h0 = max(0, 14 * p - 7), h1 = min(IMGD - 1, 14 * p + 20);
  int w0 = max(0, 14 * q - 7), w1 = min(IMGD - 1, 14 * q + 20);
  int hl = h1 - h0 + 1, wl = w1 - w0 + 1;
  int n = hl * wl;

  const float* xb = x + (size_t)b * 3 * HW;
  const int* lb = labels + (size_t)b * HW;
  const float* Ap = A + p * IMGD;
  const float* Aq = A + q * IMGD;

  for (int idx = tid; idx < n; idx += 256) {
    int dh = idx / wl;
    int hh = h0 + dh;
    int ww = w0 + (idx - dh * wl);
    int i = hh * IMGD + ww;
    float wgt = Ap[hh] * Aq[ww];
    int k = lb[i];
    atomicAdd(&sk[k * 3 + 0], wgt * xb[i]);
    atomicAdd(&sk[k * 3 + 1], wgt * xb[HW + i]);
    atomicAdd(&sk[k * 3 + 2], wgt * xb[2 * HW + i]);
  }
  __syncthreads();

  float* outb = out + (size_t)b * OUT_PER_B;
  int base = p * 48 + q * 3;
  for (int t = tid; t < NK * 3; t += 256) {
    int k = t / 3, c = t - 3 * k;
    int f = k * 768 + base + c;           // flat [K,P,P,C] index
    outb[(f & 255) * 300 + (f >> 8)] = sk[t];  // view(B,300,256) + transpose
  }
}

extern "C" void kernel_launch(void* const* d_in, const int* in_sizes, int n_in,
                              void* d_out, int out_size, void* d_ws, size_t ws_size,
                              hipStream_t stream) {
  const float* x = (const float*)d_in[0];
  float* out = (float*)d_out;
  char* ws = (char*)d_ws;
  // ws layout:
  float* A        = (float*)(ws);              // 14336 B
  float* centers  = (float*)(ws + 16384);      // 16000 B
  float* c2g      = (float*)(ws + 49152);      // 3200 B
  int*   labels   = (int*)(ws + 90112);        // 1605632 B
  float* partials = (float*)(ws + 1703936);    // 8*100*6*131*4 = 2515200 B

  build_A_kernel<<<16, 256, 0, stream>>>(A);
  init_centers_kernel<<<NB, 128, 0, stream>>>(x, centers, c2g);

  dim3 cgrid(NCHUNK, NB);         // 131 x 8
  for (int it = 0; it < 10; ++it) {
    iter_kernel<<<cgrid, 128, 0, stream>>>(x, centers, c2g, partials);
    combine_update_kernel<<<NB * NK, 128, 0, stream>>>(centers, partials, c2g);
  }
  dim3 agrid(98, NB);             // 98*512 = 50176 exact
  assign_kernel<<<agrid, 256, 0, stream>>>(x, centers, c2g, labels);

  dim3 egrid(256, NB);            // (p*16+q) x b
  embed_kernel<<<egrid, 256, 0, stream>>>(x, labels, A, out);
}